// Round 3
// baseline (370.145 us; speedup 1.0000x reference)
//
#include <hip/hip_runtime.h>
#include <hip/hip_bf16.h>
#include <math.h>

// ---------------- problem constants ----------------
#define NB 32
#define QL 32
#define DL 1024
#define EMB 300
#define EMBP 320            // padded embed dim (zeros 300..319)
#define OD 128
#define KNUM 21
#define VOCAB 50000

typedef short short8 __attribute__((ext_vector_type(8)));
typedef float floatx4 __attribute__((ext_vector_type(4)));

// workspace layout (in float units)
static const size_t WP_OFF = 0;                        // packed bf16 weights
static const size_t EMB16_OFF = 122880;                // bf16 emb [VOCAB][320]
static const size_t QENC_OFF = 8122880;
static const size_t QENC_SZ = NB * QL * OD;            // 131072
static const size_t DENC_OFF = QENC_OFF + 3 * QENC_SZ;
static const size_t DENC_SZ = (size_t)NB * DL * OD;    // 4194304
static const size_t ACC_OFF = DENC_OFF + 3 * DENC_SZ;
static const int ACC_SZ = 9 * NB * QL * KNUM;          // 193536

__device__ __constant__ int WPOFF_C[3] = {0, 40960, 122880};

// ---------------- emb fp32 -> bf16, pad 300 -> 320 ----------------
__global__ void prep_emb_kernel(const float* __restrict__ emb, ushort* __restrict__ emb16) {
    int idx = blockIdx.x * 256 + threadIdx.x;
    if (idx >= VOCAB * 40) return;
    int r = idx / 40;
    int c0 = (idx - r * 40) * 8;
    ushort v[8];
#pragma unroll
    for (int i = 0; i < 8; ++i) {
        int c = c0 + i;
        float f = (c < EMB) ? emb[r * EMB + c] : 0.f;
        __hip_bfloat16 h = __float2bfloat16(f);
        v[i] = *reinterpret_cast<ushort*>(&h);
    }
    *reinterpret_cast<uint4*>(emb16 + (size_t)r * EMBP + c0) = *reinterpret_cast<uint4*>(v);
}

// ---------------- weights -> bf16, layout [o][j*320+c] ----------------
__global__ void prep_w_kernel(const float* __restrict__ w1,
                              const float* __restrict__ w2,
                              const float* __restrict__ w3,
                              ushort* __restrict__ wp) {
    int idx = blockIdx.x * 256 + threadIdx.x;
    if (idx >= 245760) return;
    const float* src;
    int k, rel, base;
    if (idx < 40960)        { k = 1; rel = idx;          src = w1; base = 0; }
    else if (idx < 122880)  { k = 2; rel = idx - 40960;  src = w2; base = 40960; }
    else                    { k = 3; rel = idx - 122880; src = w3; base = 122880; }
    int kd = 320 * k;
    int o = rel / kd;
    int jc = rel - o * kd;
    int j = jc / EMBP;
    int c = jc - j * EMBP;
    float f = (c < EMB) ? src[(o * EMB + c) * k + j] : 0.f;
    __hip_bfloat16 h = __float2bfloat16(f);
    wp[base + rel] = *reinterpret_cast<ushort*>(&h);
}

// ---------------- fused gather + conv (bf16 MFMA) + bias + relu + row-normalize + mask ----------------
__global__ __launch_bounds__(256) void conv_mfma(const ushort* __restrict__ emb16,
                                                 const int* __restrict__ ids,
                                                 const float* __restrict__ mask,
                                                 int L, int Lmax, size_t enc_sz,
                                                 const ushort* __restrict__ wp,
                                                 const float* __restrict__ b1,
                                                 const float* __restrict__ b2,
                                                 const float* __restrict__ b3,
                                                 float* __restrict__ enc) {
    __shared__ ushort As[128 * 72];
    __shared__ ushort Bs[128 * 72];
    __shared__ float rowsum[2][128];

    const int tid = threadIdx.x;
    const int b = blockIdx.y;
    const int z = blockIdx.z;
    const int Kdim = EMBP * (z + 1);
    const int NCH = Kdim >> 6;
    const int l0 = blockIdx.x * 128;
    const int Lk = L - z;
    const ushort* wpk = wp + WPOFF_C[z];
    const float* bias = (z == 0) ? b1 : ((z == 1) ? b2 : b3);
    float* out = enc + (size_t)z * enc_sz;

    const int wave = tid >> 6;
    const int lane = tid & 63;
    const int wm = wave >> 1;
    const int wn = wave & 1;
    const int l15 = lane & 15;
    const int quad = lane >> 4;

    const int g = tid & 7;
    const int mr = tid >> 3;

    floatx4 acc[4][4];
#pragma unroll
    for (int i = 0; i < 4; ++i)
#pragma unroll
        for (int j = 0; j < 4; ++j) acc[i][j] = (floatx4)0.f;

    for (int ch = 0; ch < NCH; ++ch) {
        const int k0 = ch << 6;
        const int jj = k0 / EMBP;
        const int c0 = k0 - jj * EMBP;
#pragma unroll
        for (int p = 0; p < 4; ++p) {
            int m = mr + (p << 5);
            int l = l0 + m + jj;
            if (l > L - 1) l = L - 1;
            int rid = ids[b * L + l];
            uint4 av = *reinterpret_cast<const uint4*>(emb16 + (size_t)rid * EMBP + c0 + (g << 3));
            *reinterpret_cast<uint4*>(&As[m * 72 + (g << 3)]) = av;
            uint4 bv = *reinterpret_cast<const uint4*>(wpk + (size_t)m * Kdim + k0 + (g << 3));
            *reinterpret_cast<uint4*>(&Bs[m * 72 + (g << 3)]) = bv;
        }
        __syncthreads();
#pragma unroll
        for (int h = 0; h < 2; ++h) {
            short8 af[4], bf[4];
#pragma unroll
            for (int i = 0; i < 4; ++i) {
                int m = wm * 64 + i * 16 + l15;
                af[i] = *reinterpret_cast<const short8*>(&As[m * 72 + h * 32 + (quad << 3)]);
                int n = wn * 64 + i * 16 + l15;
                bf[i] = *reinterpret_cast<const short8*>(&Bs[n * 72 + h * 32 + (quad << 3)]);
            }
#pragma unroll
            for (int i = 0; i < 4; ++i)
#pragma unroll
                for (int j = 0; j < 4; ++j)
                    acc[i][j] = __builtin_amdgcn_mfma_f32_16x16x32_bf16(af[i], bf[j], acc[i][j], 0, 0, 0);
        }
        __syncthreads();
    }

    // epilogue: bias + relu (in acc), then row sum-of-squares
    float bv[4];
#pragma unroll
    for (int j = 0; j < 4; ++j) bv[j] = bias[wn * 64 + j * 16 + l15];
#pragma unroll
    for (int i = 0; i < 4; ++i)
#pragma unroll
        for (int r = 0; r < 4; ++r) {
            float p = 0.f;
#pragma unroll
            for (int j = 0; j < 4; ++j) {
                float y = fmaxf(acc[i][j][r] + bv[j], 0.f);
                acc[i][j][r] = y;
                p += y * y;
            }
            // reduce over l15 (16 lanes share a row within this wave half)
#pragma unroll
            for (int m = 1; m < 16; m <<= 1) p += __shfl_xor(p, m, 64);
            if (l15 == 0) rowsum[wn][wm * 64 + i * 16 + quad * 4 + r] = p;
        }
    __syncthreads();

#pragma unroll
    for (int i = 0; i < 4; ++i) {
        int mbase = wm * 64 + i * 16 + quad * 4;
#pragma unroll
        for (int r = 0; r < 4; ++r) {
            int row = mbase + r;
            int l = l0 + row;
            if (l < Lk) {
                float tot = rowsum[0][row] + rowsum[1][row];
                float mv = mask[b * L + l];
                float sc = mv / (sqrtf(tot) + 1e-13f);
                float* op = out + ((size_t)(b * Lmax + l)) * OD + wn * 64 + l15;
#pragma unroll
                for (int j = 0; j < 4; ++j)
                    op[j * 16] = acc[i][j][r] * sc;
            }
        }
    }
}

// ---------------- matcher: dot tile + register-accumulated gaussian histogram ----------------
// grid: (vtile=8, b=32, pair=9), block 256.
__global__ __launch_bounds__(256) void matcher_kernel(const float* __restrict__ qenc,
                                                      const float* __restrict__ denc,
                                                      float* __restrict__ accb) {
    __shared__ float lds[5376];        // 21.5 KB
    float* Qs = lds;                   // [32 k][36 q]
    float* Vs = lds + 1152;            // [32 k][132 v]
    float* Sm = lds;                   // [32 q][132 v], aliased after dots

    const int tid = threadIdx.x;
    const int p = blockIdx.z;
    const int b = blockIdx.y;
    const int v0 = blockIdx.x * 128;
    const int qi = p / 3;
    const int di = p - qi * 3;
    const int Vk = 1024 - di;
    const float* qptr = qenc + qi * QENC_SZ + (size_t)b * (QL * OD);
    const float* vptr = denc + di * DENC_SZ + (size_t)b * (DL * OD);

    const int vg32 = tid & 31;
    const int qg = tid >> 5;
    const int vt = vg32 * 4;
    const int qt = qg * 4;
    float acc[4][4];
#pragma unroll
    for (int i = 0; i < 4; ++i)
#pragma unroll
        for (int j = 0; j < 4; ++j) acc[i][j] = 0.f;

    const int ks = tid & 31;
    const int rb = tid >> 5;           // 0..7

    for (int ch = 0; ch < 4; ++ch) {
        const int k0 = ch * 32;
#pragma unroll
        for (int pass = 0; pass < 4; ++pass) {
            int q = rb + pass * 8;
            Qs[ks * 36 + q] = qptr[q * OD + k0 + ks];
        }
#pragma unroll
        for (int pass = 0; pass < 16; ++pass) {
            int v = rb + pass * 8;
            Vs[ks * 132 + v] = vptr[(size_t)(v0 + v) * OD + k0 + ks];
        }
        __syncthreads();
#pragma unroll 8
        for (int k = 0; k < 32; ++k) {
            float4 qv = *reinterpret_cast<const float4*>(&Qs[k * 36 + qt]);
            float4 vv = *reinterpret_cast<const float4*>(&Vs[k * 132 + vt]);
            float qa[4] = {qv.x, qv.y, qv.z, qv.w};
            float va[4] = {vv.x, vv.y, vv.z, vv.w};
#pragma unroll
            for (int i = 0; i < 4; ++i)
#pragma unroll
                for (int j = 0; j < 4; ++j) acc[i][j] += qa[i] * va[j];
        }
        __syncthreads();
    }
    // S tile to LDS (aliases Qs/Vs)
#pragma unroll
    for (int i = 0; i < 4; ++i)
        *reinterpret_cast<float4*>(&Sm[(qt + i) * 132 + vt]) =
            make_float4(acc[i][0], acc[i][1], acc[i][2], acc[i][3]);
    __syncthreads();

    // gaussian phase: thread = (q, 16-v strip); 21 register accumulators
    const int q = tid >> 3;
    const int vg = tid & 7;
    const int vbase = v0 + vg * 16;
    float kacc[KNUM];
#pragma unroll
    for (int t = 0; t < KNUM; ++t) kacc[t] = 0.f;
    const float* srow = &Sm[q * 132 + vg * 16];

#pragma unroll
    for (int v4 = 0; v4 < 4; ++v4) {
        float4 sv = *reinterpret_cast<const float4*>(&srow[v4 * 4]);
        float se[4] = {sv.x, sv.y, sv.z, sv.w};
#pragma unroll
        for (int e = 0; e < 4; ++e) {
            float s = (vbase + v4 * 4 + e < Vk) ? se[e] : 1.0e4f;
            float s2 = s * s;
            float d1 = s - 1.0f;
            kacc[0] += __builtin_exp2f(-721347.56f * (d1 * d1));   // sigma=0.001 kernel, exact near s=1
#pragma unroll
            for (int t = 1; t < KNUM; ++t) {
                const float mu = 0.95f - 0.1f * (float)(t - 1);
                const float Bc = 144.26950408f * mu;               // 100*mu*log2e
                const float Cc = -72.13475204f * mu * mu;          // -50*mu^2*log2e
                float arg = fmaf(Bc, s, fmaf(-72.13475204f, s2, Cc));
                kacc[t] += __builtin_exp2f(arg);
            }
        }
    }
    // reduce across the 8 v-strips sharing q
#pragma unroll
    for (int t = 0; t < KNUM; ++t) {
#pragma unroll
        for (int m = 1; m < 8; m <<= 1) kacc[t] += __shfl_xor(kacc[t], m, 64);
    }
    if (vg == 0) {
        float* dst = &accb[((p * NB + b) * QL + q) * KNUM];
#pragma unroll
        for (int t = 0; t < KNUM; ++t) atomicAdd(&dst[t], kacc[t]);
    }
}

// ---------------- finalize ----------------
__global__ void finalize_kernel(const float* __restrict__ accb,
                                const float* __restrict__ qmask,
                                const float* __restrict__ dw,
                                const float* __restrict__ db,
                                float* __restrict__ out) {
    __shared__ float prod[192];
    int b = blockIdx.x;
    int tid = threadIdx.x;
    if (tid < 189) {
        int pq = tid / 21;
        int t = tid - pq * 21;
        int qi = pq / 3;
        int Qk = 32 - qi;
        const float* ab = accb + ((pq * NB + b) * QL) * KNUM + t;
        float s = 0.f;
        for (int q = 0; q < Qk; ++q)
            s += logf(fmaxf(ab[q * KNUM], 1e-10f)) * qmask[b * QL + q];
        float lg = s * 0.01f;
        out[NB + b * 189 + tid] = lg;
        prod[tid] = lg * dw[tid];
    }
    __syncthreads();
    if (tid == 0) {
        float sc = db[0];
        for (int i = 0; i < 189; ++i) sc += prod[i];
        out[b] = sc;
    }
}

// ---------------- launcher ----------------
extern "C" void kernel_launch(void* const* d_in, const int* in_sizes, int n_in,
                              void* d_out, int out_size, void* d_ws, size_t ws_size,
                              hipStream_t stream) {
    const int* qids = (const int*)d_in[0];
    const float* qmask = (const float*)d_in[1];
    const int* dids = (const int*)d_in[2];
    const float* dmask = (const float*)d_in[3];
    const float* emb = (const float*)d_in[4];
    const float* w1 = (const float*)d_in[5];
    const float* b1 = (const float*)d_in[6];
    const float* w2 = (const float*)d_in[7];
    const float* b2 = (const float*)d_in[8];
    const float* w3 = (const float*)d_in[9];
    const float* b3 = (const float*)d_in[10];
    const float* dw = (const float*)d_in[11];
    const float* db = (const float*)d_in[12];
    float* out = (float*)d_out;
    float* ws = (float*)d_ws;

    ushort* wp = (ushort*)(ws + WP_OFF);
    ushort* emb16 = (ushort*)(ws + EMB16_OFF);
    float* qenc = ws + QENC_OFF;
    float* denc = ws + DENC_OFF;
    float* accb = ws + ACC_OFF;

    hipMemsetAsync(accb, 0, ACC_SZ * sizeof(float), stream);
    prep_emb_kernel<<<(VOCAB * 40 + 255) / 256, 256, 0, stream>>>(emb, emb16);
    prep_w_kernel<<<960, 256, 0, stream>>>(w1, w2, w3, wp);

    conv_mfma<<<dim3(8, NB, 3), 256, 0, stream>>>(emb16, dids, dmask, DL, DL, DENC_SZ, wp, b1, b2, b3, denc);
    conv_mfma<<<dim3(1, NB, 3), 256, 0, stream>>>(emb16, qids, qmask, QL, QL, QENC_SZ, wp, b1, b2, b3, qenc);

    matcher_kernel<<<dim3(8, NB, 9), 256, 0, stream>>>(qenc, denc, accb);
    finalize_kernel<<<NB, 256, 0, stream>>>(accb, qmask, dw, db, out);
}

// Round 4
// 329.778 us; speedup vs baseline: 1.1224x; 1.1224x over previous
//
#include <hip/hip_runtime.h>
#include <hip/hip_bf16.h>
#include <math.h>

// ---------------- problem constants ----------------
#define NB 32
#define QL 32
#define DL 1024
#define EMB 300
#define EMBP 320            // padded K-dim per tap (zeros 300..319)
#define OD 128
#define KNUM 21
#define VOCAB 50000

typedef short short8 __attribute__((ext_vector_type(8)));
typedef float floatx4 __attribute__((ext_vector_type(4)));

// workspace layout (in float units)
static const size_t WP_OFF = 0;                        // packed bf16 weights
static const size_t QENC_OFF = 8122880;
static const size_t QENC_SZ = NB * QL * OD;            // 131072
static const size_t DENC_OFF = QENC_OFF + 3 * QENC_SZ;
static const size_t DENC_SZ = (size_t)NB * DL * OD;    // 4194304
static const size_t ACC_OFF = DENC_OFF + 3 * DENC_SZ;
static const int ACC_SZ = 9 * NB * QL * KNUM;          // 193536

__device__ __constant__ int WPOFF_C[3] = {0, 40960, 122880};

// ---------------- weights -> bf16, layout [o][j*320+c] ----------------
__global__ void prep_w_kernel(const float* __restrict__ w1,
                              const float* __restrict__ w2,
                              const float* __restrict__ w3,
                              ushort* __restrict__ wp) {
    int idx = blockIdx.x * 256 + threadIdx.x;
    if (idx >= 245760) return;
    const float* src;
    int k, rel, base;
    if (idx < 40960)        { k = 1; rel = idx;          src = w1; base = 0; }
    else if (idx < 122880)  { k = 2; rel = idx - 40960;  src = w2; base = 40960; }
    else                    { k = 3; rel = idx - 122880; src = w3; base = 122880; }
    int kd = 320 * k;
    int o = rel / kd;
    int jc = rel - o * kd;
    int j = jc / EMBP;
    int c = jc - j * EMBP;
    float f = (c < EMB) ? src[(o * EMB + c) * k + j] : 0.f;
    __hip_bfloat16 h = __float2bfloat16(f);
    wp[base + rel] = *reinterpret_cast<ushort*>(&h);
}

// ---------------- fused gather(fp32->bf16) + conv MFMA + bias + relu + normalize + mask ----------------
__global__ __launch_bounds__(256) void conv_mfma(const float* __restrict__ emb,
                                                 const int* __restrict__ ids,
                                                 const float* __restrict__ mask,
                                                 int L, int Lmax, size_t enc_sz,
                                                 const ushort* __restrict__ wp,
                                                 const float* __restrict__ b1,
                                                 const float* __restrict__ b2,
                                                 const float* __restrict__ b3,
                                                 float* __restrict__ enc) {
    __shared__ ushort As[128 * 72];
    __shared__ ushort Bs[128 * 72];
    __shared__ float rowsum[2][128];

    const int tid = threadIdx.x;
    const int b = blockIdx.y;
    const int z = blockIdx.z;
    const int Kdim = EMBP * (z + 1);
    const int NCH = Kdim >> 6;
    const int l0 = blockIdx.x * 128;
    const int Lk = L - z;
    const ushort* wpk = wp + WPOFF_C[z];
    const float* bias = (z == 0) ? b1 : ((z == 1) ? b2 : b3);
    float* out = enc + (size_t)z * enc_sz;

    const int wave = tid >> 6;
    const int lane = tid & 63;
    const int wm = wave >> 1;
    const int wn = wave & 1;
    const int l15 = lane & 15;
    const int quad = lane >> 4;

    const int g = tid & 7;
    const int mr = tid >> 3;

    floatx4 acc[4][4];
#pragma unroll
    for (int i = 0; i < 4; ++i)
#pragma unroll
        for (int j = 0; j < 4; ++j) acc[i][j] = (floatx4)0.f;

    for (int ch = 0; ch < NCH; ++ch) {
        const int k0 = ch << 6;
        const int jj = k0 / EMBP;     // conv tap (chunks never straddle: 320/64 = 5)
        const int c0 = k0 - jj * EMBP;
        const int cbase = c0 + (g << 3);
#pragma unroll
        for (int p = 0; p < 4; ++p) {
            int m = mr + (p << 5);
            // A: gather embedding row, convert fp32 -> bf16 in-register
            int l = l0 + m + jj;
            if (l > L - 1) l = L - 1;
            int rid = ids[b * L + l];
            const float* erow = emb + (size_t)rid * EMB;
            ushort v8[8];
            if (cbase + 8 <= EMB) {
                float4 f0 = *reinterpret_cast<const float4*>(erow + cbase);
                float4 f1 = *reinterpret_cast<const float4*>(erow + cbase + 4);
                float fv[8] = {f0.x, f0.y, f0.z, f0.w, f1.x, f1.y, f1.z, f1.w};
#pragma unroll
                for (int i = 0; i < 8; ++i) {
                    __hip_bfloat16 h = __float2bfloat16(fv[i]);
                    v8[i] = *reinterpret_cast<ushort*>(&h);
                }
            } else {
#pragma unroll
                for (int i = 0; i < 8; ++i) {
                    int c = cbase + i;
                    float f = (c < EMB) ? erow[c] : 0.f;
                    __hip_bfloat16 h = __float2bfloat16(f);
                    v8[i] = *reinterpret_cast<ushort*>(&h);
                }
            }
            *reinterpret_cast<uint4*>(&As[m * 72 + (g << 3)]) = *reinterpret_cast<uint4*>(v8);
            // B: weight row
            uint4 bv = *reinterpret_cast<const uint4*>(wpk + (size_t)m * Kdim + k0 + (g << 3));
            *reinterpret_cast<uint4*>(&Bs[m * 72 + (g << 3)]) = bv;
        }
        __syncthreads();
#pragma unroll
        for (int h = 0; h < 2; ++h) {
            short8 af[4], bf[4];
#pragma unroll
            for (int i = 0; i < 4; ++i) {
                int m = wm * 64 + i * 16 + l15;
                af[i] = *reinterpret_cast<const short8*>(&As[m * 72 + h * 32 + (quad << 3)]);
                int n = wn * 64 + i * 16 + l15;
                bf[i] = *reinterpret_cast<const short8*>(&Bs[n * 72 + h * 32 + (quad << 3)]);
            }
#pragma unroll
            for (int i = 0; i < 4; ++i)
#pragma unroll
                for (int j = 0; j < 4; ++j)
                    acc[i][j] = __builtin_amdgcn_mfma_f32_16x16x32_bf16(af[i], bf[j], acc[i][j], 0, 0, 0);
        }
        __syncthreads();
    }

    // epilogue: bias + relu, row sum-of-squares, normalize + mask
    float bv[4];
#pragma unroll
    for (int j = 0; j < 4; ++j) bv[j] = bias[wn * 64 + j * 16 + l15];
#pragma unroll
    for (int i = 0; i < 4; ++i)
#pragma unroll
        for (int r = 0; r < 4; ++r) {
            float p = 0.f;
#pragma unroll
            for (int j = 0; j < 4; ++j) {
                float y = fmaxf(acc[i][j][r] + bv[j], 0.f);
                acc[i][j][r] = y;
                p += y * y;
            }
#pragma unroll
            for (int m = 1; m < 16; m <<= 1) p += __shfl_xor(p, m, 64);
            if (l15 == 0) rowsum[wn][wm * 64 + i * 16 + quad * 4 + r] = p;
        }
    __syncthreads();

#pragma unroll
    for (int i = 0; i < 4; ++i) {
        int mbase = wm * 64 + i * 16 + quad * 4;
#pragma unroll
        for (int r = 0; r < 4; ++r) {
            int row = mbase + r;
            int l = l0 + row;
            if (l < Lk) {
                float tot = rowsum[0][row] + rowsum[1][row];
                float mv = mask[b * L + l];
                float sc = mv / (sqrtf(tot) + 1e-13f);
                float* op = out + ((size_t)(b * Lmax + l)) * OD + wn * 64 + l15;
#pragma unroll
                for (int j = 0; j < 4; ++j)
                    op[j * 16] = acc[i][j][r] * sc;
            }
        }
    }
}

// ---------------- matcher: dot tile + gaussian histogram ----------------
// grid: (vtile=8, b=32, pair=9), block 256. LDS 21.3 KB -> 7 blocks/CU.
__global__ __launch_bounds__(256) void matcher_kernel(const float* __restrict__ qenc,
                                                      const float* __restrict__ denc,
                                                      float* __restrict__ accb) {
    __shared__ float lds[5440];        // 21.3 KB
    float* Qs = lds;                   // [32 k][36 q]
    float* Vs = lds + 1152;            // [32 k][132 v]
    float* Sm = lds;                   // [32 q][136 v], aliased after dots (rows 16B-aligned)

    const int tid = threadIdx.x;
    const int p = blockIdx.z;
    const int b = blockIdx.y;
    const int v0 = blockIdx.x * 128;
    const int qi = p / 3;
    const int di = p - qi * 3;
    const int Vk = 1024 - di;
    const float* qptr = qenc + qi * QENC_SZ + (size_t)b * (QL * OD);
    const float* vptr = denc + di * DENC_SZ + (size_t)b * (DL * OD);

    const int vg32 = tid & 31;
    const int qg = tid >> 5;
    const int vt = vg32 * 4;
    const int qt = qg * 4;
    float acc[4][4];
#pragma unroll
    for (int i = 0; i < 4; ++i)
#pragma unroll
        for (int j = 0; j < 4; ++j) acc[i][j] = 0.f;

    const int ks = tid & 31;
    const int rb = tid >> 5;           // 0..7

    for (int ch = 0; ch < 4; ++ch) {
        const int k0 = ch * 32;
#pragma unroll
        for (int pass = 0; pass < 4; ++pass) {
            int q = rb + pass * 8;
            Qs[ks * 36 + q] = qptr[q * OD + k0 + ks];
        }
#pragma unroll
        for (int pass = 0; pass < 16; ++pass) {
            int v = rb + pass * 8;
            Vs[ks * 132 + v] = vptr[(size_t)(v0 + v) * OD + k0 + ks];
        }
        __syncthreads();
#pragma unroll 8
        for (int k = 0; k < 32; ++k) {
            float4 qv = *reinterpret_cast<const float4*>(&Qs[k * 36 + qt]);
            float4 vv = *reinterpret_cast<const float4*>(&Vs[k * 132 + vt]);
            float qa[4] = {qv.x, qv.y, qv.z, qv.w};
            float va[4] = {vv.x, vv.y, vv.z, vv.w};
#pragma unroll
            for (int i = 0; i < 4; ++i)
#pragma unroll
                for (int j = 0; j < 4; ++j) acc[i][j] += qa[i] * va[j];
        }
        __syncthreads();
    }
    // store S tile; out-of-range v poisoned with 1e4 (all kernels -> exactly 0)
    const int vmax = min(128, Vk - v0);
#pragma unroll
    for (int i = 0; i < 4; ++i) {
        float4 sv;
        sv.x = (vt + 0 < vmax) ? acc[i][0] : 1.0e4f;
        sv.y = (vt + 1 < vmax) ? acc[i][1] : 1.0e4f;
        sv.z = (vt + 2 < vmax) ? acc[i][2] : 1.0e4f;
        sv.w = (vt + 3 < vmax) ? acc[i][3] : 1.0e4f;
        *reinterpret_cast<float4*>(&Sm[(qt + i) * 136 + vt]) = sv;
    }
    __syncthreads();

    // gaussian phase: thread = (q, t), ONE accumulator (no spill), float4 LDS reads
    for (int idx = tid; idx < 32 * KNUM; idx += 256) {
        int q = idx & 31;
        int t = idx >> 5;
        float mu = (t == 0) ? 1.0f : 0.95f - 0.1f * (float)(t - 1);
        float Am = (t == 0) ? -721347.56f : -72.13475204f;   // -log2e/(2 sigma^2)
        const float* srow = &Sm[q * 136];
        float a = 0.f;
#pragma unroll 8
        for (int j = 0; j < 32; ++j) {
            float4 s4 = *reinterpret_cast<const float4*>(&srow[4 * j]);
            float d;
            d = s4.x - mu; a += __builtin_exp2f(Am * d * d);
            d = s4.y - mu; a += __builtin_exp2f(Am * d * d);
            d = s4.z - mu; a += __builtin_exp2f(Am * d * d);
            d = s4.w - mu; a += __builtin_exp2f(Am * d * d);
        }
        atomicAdd(&accb[((p * NB + b) * QL + q) * KNUM + t], a);
    }
}

// ---------------- finalize ----------------
__global__ void finalize_kernel(const float* __restrict__ accb,
                                const float* __restrict__ qmask,
                                const float* __restrict__ dw,
                                const float* __restrict__ db,
                                float* __restrict__ out) {
    __shared__ float prod[192];
    int b = blockIdx.x;
    int tid = threadIdx.x;
    if (tid < 189) {
        int pq = tid / 21;
        int t = tid - pq * 21;
        int qi = pq / 3;
        int Qk = 32 - qi;
        const float* ab = accb + ((pq * NB + b) * QL) * KNUM + t;
        float s = 0.f;
        for (int q = 0; q < Qk; ++q)
            s += logf(fmaxf(ab[q * KNUM], 1e-10f)) * qmask[b * QL + q];
        float lg = s * 0.01f;
        out[NB + b * 189 + tid] = lg;
        prod[tid] = lg * dw[tid];
    }
    __syncthreads();
    if (tid == 0) {
        float sc = db[0];
        for (int i = 0; i < 189; ++i) sc += prod[i];
        out[b] = sc;
    }
}

// ---------------- launcher ----------------
extern "C" void kernel_launch(void* const* d_in, const int* in_sizes, int n_in,
                              void* d_out, int out_size, void* d_ws, size_t ws_size,
                              hipStream_t stream) {
    const int* qids = (const int*)d_in[0];
    const float* qmask = (const float*)d_in[1];
    const int* dids = (const int*)d_in[2];
    const float* dmask = (const float*)d_in[3];
    const float* emb = (const float*)d_in[4];
    const float* w1 = (const float*)d_in[5];
    const float* b1 = (const float*)d_in[6];
    const float* w2 = (const float*)d_in[7];
    const float* b2 = (const float*)d_in[8];
    const float* w3 = (const float*)d_in[9];
    const float* b3 = (const float*)d_in[10];
    const float* dw = (const float*)d_in[11];
    const float* db = (const float*)d_in[12];
    float* out = (float*)d_out;
    float* ws = (float*)d_ws;

    ushort* wp = (ushort*)(ws + WP_OFF);
    float* qenc = ws + QENC_OFF;
    float* denc = ws + DENC_OFF;
    float* accb = ws + ACC_OFF;

    hipMemsetAsync(accb, 0, ACC_SZ * sizeof(float), stream);
    prep_w_kernel<<<960, 256, 0, stream>>>(w1, w2, w3, wp);

    conv_mfma<<<dim3(8, NB, 3), 256, 0, stream>>>(emb, dids, dmask, DL, DL, DENC_SZ, wp, b1, b2, b3, denc);
    conv_mfma<<<dim3(1, NB, 3), 256, 0, stream>>>(emb, qids, qmask, QL, QL, QENC_SZ, wp, b1, b2, b3, qenc);

    matcher_kernel<<<dim3(8, NB, 9), 256, 0, stream>>>(qenc, denc, accb);
    finalize_kernel<<<NB, 256, 0, stream>>>(accb, qmask, dw, db, out);
}